// Round 14
// baseline (56.159 us; speedup 1.0000x reference)
//
#include <hip/hip_runtime.h>
#include <hip/hip_bf16.h>

// PositionAwareARCEncoder fused kernels.
// B=32768, H=W=5, NC=4, E=64, HID=128, OUT=128, NH=4, HD=16.
//
// R13 = R12 preps (proven ~6us) + arc_fused at grid 683 x 3 tiles with
// __launch_bounds__(256,3): grid was the occupancy cap (512 = exactly
// 2 blocks/CU); 683 blocks all-resident at 3 blocks/CU gives +50% TLP
// without a second dispatch wave (R9's mistake).

typedef __attribute__((ext_vector_type(8))) short short8v;
typedef __attribute__((ext_vector_type(4))) float float4v;

static __device__ __forceinline__ short f2bfs(float f) {
  __hip_bfloat16 h = __float2bfloat16(f);   // native cvt, RNE
  return *reinterpret_cast<short*>(&h);
}
static __device__ __forceinline__ float bfs2f(short s) {
  return __uint_as_float(((unsigned)(unsigned short)s) << 16);
}
static __device__ __forceinline__ unsigned short f2bf(float f) {
  unsigned int u = __float_as_uint(f);
  unsigned int r = (u + 0x7fffu + ((u >> 16) & 1u)) >> 16;
  return (unsigned short)r;
}

// ---------------- prepE: MLPs + all MLP-independent tables (flat) ---------
__global__ __launch_bounds__(128) void prepE(
    const float* __restrict__ color_embed, const float* __restrict__ row_embed,
    const float* __restrict__ col_embed,
    const float* __restrict__ ip_w1, const float* __restrict__ ip_b1,
    const float* __restrict__ ip_w2, const float* __restrict__ ip_b2,
    const float* __restrict__ op_w1, const float* __restrict__ op_b1,
    const float* __restrict__ op_w2, const float* __restrict__ op_b2,
    const float* __restrict__ q_w, const float* __restrict__ q_b,
    const float* __restrict__ o_w, const float* __restrict__ o_b,
    const float* __restrict__ cb_w1, const float* __restrict__ cb_b1,
    const float* __restrict__ cb_w2,
    float* __restrict__ inpval, float* __restrict__ outval,
    float* __restrict__ qtab, float* __restrict__ cpeproj,
    float* __restrict__ bias1,
    unsigned short* __restrict__ wovT, unsigned short* __restrict__ cbw2T) {
  const int bid = blockIdx.x, t = threadIdx.x;
  if (bid < 200) {                         // MLP for cij (input / output path)
    __shared__ float feat[128];
    __shared__ float h1[128];
    const int path = bid / 100;
    const int cij = bid % 100;
    const int c = cij / 25, ij = cij % 25, gi = ij / 5, gj = ij % 5;
    if (t < 64)      feat[t] = color_embed[c * 64 + t];
    else if (t < 96) feat[t] = row_embed[gi * 32 + (t - 64)];
    else             feat[t] = col_embed[gj * 32 + (t - 96)];
    __syncthreads();
    const float* w1 = path ? op_w1 : ip_w1;
    const float* b1 = path ? op_b1 : ip_b1;
    float acc = b1[t];
#pragma unroll 8
    for (int d = 0; d < 128; ++d) acc = fmaf(feat[d], w1[d * 128 + t], acc);
    h1[t] = fmaxf(acc, 0.f);
    __syncthreads();
    if (t < 64) {
      const float* w2 = path ? op_w2 : ip_w2;
      const float* b2 = path ? op_b2 : ip_b2;
      float v = b2[t];
#pragma unroll 8
      for (int d = 0; d < 128; ++d) v = fmaf(h1[d], w2[d * 64 + t], v);
      (path ? outval : inpval)[cij * 64 + t] = v;
    }
    return;
  }
  // flat one-output-per-thread sections
  const int fid = (bid - 200) * 128 + t;
  if (fid < 1664) {                        // qtab[26][64]
    const int p = fid >> 6, e2 = fid & 63;
    float a = q_b[e2];
    if (p < 25) {
      const int r = p / 5, cc = p % 5;
#pragma unroll 8
      for (int e = 0; e < 32; ++e) a = fmaf(row_embed[r * 32 + e], q_w[e * 64 + e2], a);
#pragma unroll 8
      for (int e = 0; e < 32; ++e) a = fmaf(col_embed[cc * 32 + e], q_w[(32 + e) * 64 + e2], a);
    }
    qtab[fid] = a;
  } else if (fid < 4992) {                 // cpeproj[26][128]
    const int l = fid - 1664;
    const int p = l >> 7, jj = l & 127;
    float a = 0.f;
    if (p < 25) {
      const int r = p / 5, cc = p % 5;
#pragma unroll 8
      for (int e = 0; e < 32; ++e) a = fmaf(row_embed[r * 32 + e], cb_w1[(128 + e) * 128 + jj], a);
#pragma unroll 8
      for (int e = 0; e < 32; ++e) a = fmaf(col_embed[cc * 32 + e], cb_w1[(160 + e) * 128 + jj], a);
    }
    cpeproj[l] = a;
  } else if (fid < 5120) {                 // bias1[128]
    const int jj = fid - 4992;
    float a = cb_b1[jj];
#pragma unroll 8
    for (int e = 0; e < 64; ++e) a = fmaf(o_b[e], cb_w1[e * 128 + jj], a);
    bias1[jj] = a;
  } else if (fid < 13312) {                // wovT[col 128][d 64] = bf16(o_w@cb_w1)
    const int i = fid - 5120;
    const int col = i >> 6, d = i & 63;
    float a = 0.f;
#pragma unroll 8
    for (int e = 0; e < 64; ++e) a = fmaf(o_w[d * 64 + e], cb_w1[e * 128 + col], a);
    wovT[i] = f2bf(a);
  } else if (fid < 29696) {                // cbw2T[col 128][k 128]
    const int i = fid - 13312;
    const int col = i >> 7, k = i & 127;
    cbw2T[i] = f2bf(cb_w2[k * 128 + col]);
  }
}

// ---------------- prepF: per-cij k/v/outproj + stab; aux rows --------------
__global__ __launch_bounds__(256) void prepF(
    const float* __restrict__ k_w, const float* __restrict__ k_b,
    const float* __restrict__ v_w, const float* __restrict__ v_b,
    const float* __restrict__ cb_w1,
    const float* __restrict__ qtab, const float* __restrict__ cpeproj,
    const float* __restrict__ bias1,
    const float* __restrict__ inpval, const float* __restrict__ outval,
    float* __restrict__ stab, unsigned short* __restrict__ vtabT,
    unsigned short* __restrict__ outprojBT) {
  const int bid = blockIdx.x, t = threadIdx.x;
  if (bid < 100) {
    __shared__ float kk[64];
    const int ig = bid / 25, ij = bid % 25;   // color, cell
    const float* x = inpval + bid * 64;
    if (t < 64) {                            // k column -> LDS
      float a = k_b[t];
#pragma unroll 8
      for (int e = 0; e < 64; ++e) a = fmaf(x[e], k_w[e * 64 + t], a);
      kk[t] = a;
    } else if (t < 128) {                    // v column -> vtabT direct (k'=4ij+ig)
      const int e2 = t - 64;
      float a = v_b[e2];
#pragma unroll 8
      for (int e = 0; e < 64; ++e) a = fmaf(x[e], v_w[e * 64 + e2], a);
      vtabT[(e2 >> 4) * 2048 + (e2 & 15) * 128 + 4 * ij + ig] = f2bf(a);
    } else {                                 // outproj column -> outprojBT direct
      const int col = t - 128;
      const float* y = outval + bid * 64;
      float a = 0.f;
#pragma unroll 8
      for (int e = 0; e < 64; ++e) a = fmaf(y[e], cb_w1[(64 + e) * 128 + col], a);
      outprojBT[col * 128 + 4 * ij + ig] = f2bf(a * (1.f / 25.f));
    }
    __syncthreads();
    if (t < 104) {                           // stab slice for this (ig, ij)
      const int cpe = t >> 2, h = t & 3;
      const float* qq = qtab + cpe * 64 + h * 16;
      float a = 0.f;
#pragma unroll
      for (int d = 0; d < 16; ++d) a = fmaf(qq[d], kk[h * 16 + d], a);
      stab[cpe * 400 + ig * 100 + ij * 4 + h] = a * 0.25f;
    }
  } else {                                   // aux block
    if (t < 128) {                           // outprojBT rows 100..127
      for (int p = 0; p < 26; ++p)
        outprojBT[t * 128 + 100 + p] = f2bf(cpeproj[p * 128 + t]);
      outprojBT[t * 128 + 126] = f2bf(bias1[t]);
      outprojBT[t * 128 + 127] = 0;
    } else {                                 // zero vtabT k' rows 100..127
      for (int i = t - 128; i < 1792; i += 128) {
        const int h = i / 448, r = i % 448;
        const int d = r / 28, kp = 100 + r % 28;
        vtabT[h * 2048 + d * 128 + kp] = 0;
      }
    }
  }
}

// ---------------- arc_fused: 683 blocks x 3 tiles, 3 blocks/CU ------------
__global__ __launch_bounds__(256, 3) void arc_fused(
    const int* __restrict__ obs,
    const float* __restrict__ stab,
    const unsigned short* __restrict__ vtabT,
    const unsigned short* __restrict__ outprojBT,
    const unsigned short* __restrict__ wovT,
    const unsigned short* __restrict__ cbw2T,
    const float* __restrict__ cb_b2,
    float* __restrict__ out) {
  __shared__ __align__(16) short lds_w[4 * 16 * 128];    // 16 KB, swz by batch row
  __shared__ __align__(16) short lds_og[16 * 128];       // 4 KB
  __shared__ __align__(16) short lds_raH[16 * 64];       // 2 KB
  __shared__ __align__(16) short lds_hidH[16 * 128];     // 4 KB
  __shared__ __align__(16) short lds_hidL[16 * 128];     // 4 KB

  const int tid = threadIdx.x;
  const int lane = tid & 63, wv = tid >> 6;
  const int row16 = lane & 15, g4 = lane >> 4;
  const int hh = row16 >> 2, jj = row16 & 3;
  const int b_loc = wv * 4 + g4;
  const int rsw = (row16 & 7) << 4;
  const int bswz = (b_loc & 7) << 4;
  const int tbase = blockIdx.x * 3;          // first tile (of 2048) for this block

  // ---- hoist all B-fragments into registers (constant across tiles) ----
  short8v Bv[4], Bo[2][4], Bw[2][2], Bc[2][4];
#pragma unroll
  for (int ks = 0; ks < 4; ++ks)
    Bv[ks] = *(const short8v*)(vtabT + wv * 2048 + row16 * 128 + ks * 32 + g4 * 8);
#pragma unroll
  for (int t = 0; t < 2; ++t) {
    const int col = wv * 32 + t * 16 + row16;
#pragma unroll
    for (int ks = 0; ks < 4; ++ks) {
      Bo[t][ks] = *(const short8v*)(outprojBT + col * 128 + ks * 32 + g4 * 8);
      Bc[t][ks] = *(const short8v*)(cbw2T + col * 128 + ks * 32 + g4 * 8);
    }
#pragma unroll
    for (int ks = 0; ks < 2; ++ks)
      Bw[t][ks] = *(const short8v*)(wovT + col * 64 + ks * 32 + g4 * 8);
  }
  const float bv0 = cb_b2[wv * 32 + row16];
  const float bv1 = cb_b2[wv * 32 + 16 + row16];

  // ---- one-time zero of W (covers the never-scattered pad bytes) ----
  {
    const int4 z = {0, 0, 0, 0};
    int4* pw = (int4*)lds_w;
#pragma unroll
    for (int i = 0; i < 4; ++i) pw[tid + 256 * i] = z;
  }

  // ---- prefetch obs for tile 0 ----
  int xs[4], ys[4];
#pragma unroll
  for (int e = 0; e < 4; ++e) {
    const int* ob = obs + (tbase * 16 + wv * 4 + e) * 75;
    xs[e] = ob[lane];
    ys[e] = (lane < 11) ? ob[64 + lane] : 0;
  }
  __syncthreads();   // W zero visible to all

  for (int it = 0; it < 3; ++it) {
    const int gt = tbase + it;
    if (gt >= 2048) break;
    const int b0 = gt * 16;

    // ---- decode from prefetched obs ----
    unsigned iglo = 0, ighi = 0, oglo = 0, oghi = 0;
    int cpe_sel = 0;
#pragma unroll
    for (int e = 0; e < 4; ++e) {
      const unsigned long long blo = __ballot(xs[e] & 1);
      const unsigned long long bhi = __ballot(xs[e] & 2);
      const unsigned long long bnzy = __ballot((lane < 11) && (ys[e] != 0));
      const unsigned e_iglo = (unsigned)(blo & 0x1FFFFFFull);
      const unsigned e_ighi = (unsigned)(bhi & 0x1FFFFFFull);
      const unsigned e_oglo = (unsigned)((blo >> 25) & 0x1FFFFFFull);
      const unsigned e_oghi = (unsigned)((bhi >> 25) & 0x1FFFFFFull);
      const unsigned e_mb = (unsigned)(((blo | bhi) >> 50) | (bnzy << 14));
      const int e_cpe = e_mb ? __builtin_ctz(e_mb) : 25;
      if (g4 == e) { iglo = e_iglo; ighi = e_ighi; oglo = e_oglo; oghi = e_oghi; cpe_sel = e_cpe; }
    }

    // ---- softmax: thread-per-(batch, head hh, slot jj) ----
    float ev[7];
    int ig7[7];
    {
      float sv[7];
      float mx = -1e30f;
      const float* sb = stab + cpe_sel * 400 + hh;
#pragma unroll
      for (int m = 0; m < 7; ++m) {
        const int ij = jj + 4 * m;
        if (ij < 25) {
          const int ig = ((iglo >> ij) & 1) | (((ighi >> ij) & 1) << 1);
          ig7[m] = ig;
          sv[m] = sb[ig * 100 + ij * 4];
          mx = fmaxf(mx, sv[m]);
        }
      }
      mx = fmaxf(mx, __shfl_xor(mx, 1));
      mx = fmaxf(mx, __shfl_xor(mx, 2));
      float sum = 0.f;
#pragma unroll
      for (int m = 0; m < 7; ++m) {
        const int ij = jj + 4 * m;
        if (ij < 25) { ev[m] = __expf(sv[m] - mx); sum += ev[m]; }
      }
      sum += __shfl_xor(sum, 1);
      sum += __shfl_xor(sum, 2);
      const float inv = __builtin_amdgcn_rcpf(sum);
#pragma unroll
      for (int m = 0; m < 7; ++m) ev[m] *= inv;
    }

    // ---- scatter W: thread owns k' = 4*(jj+4m)+0..3 (8B each), m=0..6 ----
#pragma unroll
    for (int m = 0; m < 7; ++m) {
      const int ij = jj + 4 * m;
      unsigned u0 = 0, u1 = 0;
      if (ij < 25) {
        const unsigned pbu = (unsigned)(unsigned short)f2bfs(ev[m]);
        const int ig = ig7[m];
        u0 = (ig == 0) ? pbu : ((ig == 1) ? (pbu << 16) : 0u);
        u1 = (ig == 2) ? pbu : ((ig == 3) ? (pbu << 16) : 0u);
      }
      const int off = (hh * 4096 + b_loc * 256 + 8 * ij) ^ bswz;
      *(int2*)((char*)lds_w + off) = make_int2((int)u0, (int)u1);
    }

    // ---- scatter OG row b_loc: thread row16 owns k' = 8*row16..+8 (16B) ----
    {
      unsigned sh[8];
#pragma unroll
      for (int u = 0; u < 8; ++u) {
        const int kp = row16 * 8 + u;
        unsigned v = 0;
        if (kp < 100) {
          const int ijq = kp >> 2;
          const int og = ((oglo >> ijq) & 1) | (((oghi >> ijq) & 1) << 1);
          v = (og == (kp & 3)) ? 0x3F80u : 0u;
        } else if (kp < 126) {
          v = (cpe_sel == kp - 100) ? 0x3F80u : 0u;
        } else if (kp == 126) {
          v = 0x3F80u;
        }
        sh[u] = v;
      }
      int4 pk;
      pk.x = (int)(sh[0] | (sh[1] << 16));
      pk.y = (int)(sh[2] | (sh[3] << 16));
      pk.z = (int)(sh[4] | (sh[5] << 16));
      pk.w = (int)(sh[6] | (sh[7] << 16));
      const int off = (b_loc * 256 + row16 * 16) ^ bswz;
      *(int4*)((char*)lds_og + off) = pk;
    }
    __syncthreads();   // B1: W/OG ready

    // ---- ra-GEMM (W rows = batches, head wv) + pre-GEMM (OG rows) ----
    float4v rc = {0.f, 0.f, 0.f, 0.f};
#pragma unroll
    for (int ks = 0; ks < 4; ++ks) {
      const short8v a = *(const short8v*)((char*)lds_w +
          ((wv * 4096 + row16 * 256 + ks * 64 + g4 * 16) ^ rsw));
      rc = __builtin_amdgcn_mfma_f32_16x16x32_bf16(a, Bv[ks], rc, 0, 0, 0);
    }
    float4v acc[2];
    acc[0] = (float4v){0.f, 0.f, 0.f, 0.f};
    acc[1] = (float4v){0.f, 0.f, 0.f, 0.f};
#pragma unroll
    for (int ks = 0; ks < 4; ++ks) {
      const short8v a = *(const short8v*)((char*)lds_og +
          ((row16 * 256 + ks * 64 + g4 * 16) ^ rsw));
      acc[0] = __builtin_amdgcn_mfma_f32_16x16x32_bf16(a, Bo[0][ks], acc[0], 0, 0, 0);
      acc[1] = __builtin_amdgcn_mfma_f32_16x16x32_bf16(a, Bo[1][ks], acc[1], 0, 0, 0);
    }

    // ---- prefetch next tile's obs (hides HBM latency under MFMA phase) ----
    if (it < 2 && gt + 1 < 2048) {
#pragma unroll
      for (int e = 0; e < 4; ++e) {
        const int* ob = obs + ((gt + 1) * 16 + wv * 4 + e) * 75;
        xs[e] = ob[lane];
        ys[e] = (lane < 11) ? ob[64 + lane] : 0;
      }
    }

    // ---- ra -> LDS (hi only) ----
#pragma unroll
    for (int r = 0; r < 4; ++r) {
      const int b = g4 * 4 + r;
      const int off = (b * 128 + (wv * 16 + row16) * 2) ^ ((b & 7) << 4);
      *(short*)((char*)lds_raH + off) = f2bfs(rc[r]);
    }
    __syncthreads();   // B2: ra ready; W/OG reads done

    // ---- wov-GEMM ----
    const short8v aH0 = *(const short8v*)((char*)lds_raH + ((row16 * 128 + g4 * 16) ^ rsw));
    const short8v aH1 = *(const short8v*)((char*)lds_raH + ((row16 * 128 + 64 + g4 * 16) ^ rsw));
#pragma unroll
    for (int t = 0; t < 2; ++t) {
      acc[t] = __builtin_amdgcn_mfma_f32_16x16x32_bf16(aH0, Bw[t][0], acc[t], 0, 0, 0);
      acc[t] = __builtin_amdgcn_mfma_f32_16x16x32_bf16(aH1, Bw[t][1], acc[t], 0, 0, 0);
    }

    // ---- relu -> hidden bf16 hi+lo ----
#pragma unroll
    for (int t = 0; t < 2; ++t) {
      const int col = wv * 32 + t * 16 + row16;
#pragma unroll
      for (int rr = 0; rr < 4; ++rr) {
        const int row = g4 * 4 + rr;
        const float hv = fmaxf(acc[t][rr], 0.f);
        const short hb = f2bfs(hv);
        const int off = (row * 256 + col * 2) ^ ((row & 7) << 4);
        *(short*)((char*)lds_hidH + off) = hb;
        *(short*)((char*)lds_hidL + off) = f2bfs(hv - bfs2f(hb));
      }
    }
    __syncthreads();   // B3: hidden ready

    // ---- out-GEMM ----
    short8v ahH[4], ahL[4];
#pragma unroll
    for (int ks = 0; ks < 4; ++ks) {
      const int off = (row16 * 256 + ks * 64 + g4 * 16) ^ rsw;
      ahH[ks] = *(const short8v*)((char*)lds_hidH + off);
      ahL[ks] = *(const short8v*)((char*)lds_hidL + off);
    }
#pragma unroll
    for (int t = 0; t < 2; ++t) {
      const int col = wv * 32 + t * 16 + row16;
      float4v c2 = {0.f, 0.f, 0.f, 0.f};
#pragma unroll
      for (int ks = 0; ks < 4; ++ks) {
        c2 = __builtin_amdgcn_mfma_f32_16x16x32_bf16(ahL[ks], Bc[t][ks], c2, 0, 0, 0);
        c2 = __builtin_amdgcn_mfma_f32_16x16x32_bf16(ahH[ks], Bc[t][ks], c2, 0, 0, 0);
      }
      const float bv = t ? bv1 : bv0;
#pragma unroll
      for (int rr = 0; rr < 4; ++rr)
        out[(b0 + g4 * 4 + rr) * 128 + col] = c2[rr] + bv;
    }
  }
}

extern "C" void kernel_launch(void* const* d_in, const int* in_sizes, int n_in,
                              void* d_out, int out_size, void* d_ws, size_t ws_size,
                              hipStream_t stream) {
  const int*   obs         = (const int*)d_in[0];
  const float* color_embed = (const float*)d_in[1];
  const float* row_embed   = (const float*)d_in[2];
  const float* col_embed   = (const float*)d_in[3];
  const float* ip_w1 = (const float*)d_in[4];
  const float* ip_b1 = (const float*)d_in[5];
  const float* ip_w2 = (const float*)d_in[6];
  const float* ip_b2 = (const float*)d_in[7];
  const float* q_w = (const float*)d_in[8];
  const float* q_b = (const float*)d_in[9];
  const float* k_w = (const float*)d_in[10];
  const float* k_b = (const float*)d_in[11];
  const float* v_w = (const float*)d_in[12];
  const float* v_b = (const float*)d_in[13];
  const float* o_w = (const float*)d_in[14];
  const float* o_b = (const float*)d_in[15];
  const float* op_w1 = (const float*)d_in[16];
  const float* op_b1 = (const float*)d_in[17];
  const float* op_w2 = (const float*)d_in[18];
  const float* op_b2 = (const float*)d_in[19];
  const float* cb_w1 = (const float*)d_in[20];
  const float* cb_b1 = (const float*)d_in[21];
  const float* cb_w2 = (const float*)d_in[22];
  const float* cb_b2 = (const float*)d_in[23];

  float* ws = (float*)d_ws;
  float* qtab    = ws;                 // 1664
  float* cpeproj = qtab + 1664;        // 3328
  float* bias1   = cpeproj + 3328;     // 128
  float* stab    = bias1 + 128;        // 10400  (ends at 15520)
  unsigned short* wovT      = (unsigned short*)(ws + 15520);  //  8192 us (4096 f)
  unsigned short* cbw2T     = (unsigned short*)(ws + 19616);  // 16384 us (8192 f)
  unsigned short* vtabT     = (unsigned short*)(ws + 27808);  //  8192 us (4096 f)
  unsigned short* outprojBT = (unsigned short*)(ws + 31904);  // 16384 us (8192 f)
  float* inpval  = ws + 40096;         // 6400
  float* outval  = inpval + 6400;      // 6400
  // total 52896 floats ~= 212 KB of d_ws

  prepE<<<432, 128, 0, stream>>>(color_embed, row_embed, col_embed,
                                 ip_w1, ip_b1, ip_w2, ip_b2,
                                 op_w1, op_b1, op_w2, op_b2,
                                 q_w, q_b, o_w, o_b, cb_w1, cb_b1, cb_w2,
                                 inpval, outval, qtab, cpeproj, bias1,
                                 wovT, cbw2T);
  prepF<<<101, 256, 0, stream>>>(k_w, k_b, v_w, v_b, cb_w1,
                                 qtab, cpeproj, bias1, inpval, outval,
                                 stab, vtabT, outprojBT);
  arc_fused<<<683, 256, 0, stream>>>(obs, stab, vtabT, outprojBT,
                                     wovT, cbw2T, cb_b2, (float*)d_out);
}

// Round 15
// 44.045 us; speedup vs baseline: 1.2750x; 1.2750x over previous
//
#include <hip/hip_runtime.h>
#include <hip/hip_bf16.h>

// PositionAwareARCEncoder fused kernels.
// B=32768, H=W=5, NC=4, E=64, HID=128, OUT=128, NH=4, HD=16.
//
// R14 = R13 minus the VGPR clamp: __launch_bounds__(256,3) forced 84 VGPR,
// but the hoisted B-frags need ~104 -> scratch spills (FETCH 35MB, arc 44us).
// Plain __launch_bounds__(256) restores natural allocation (~110-130 VGPR,
// <=128 -> 4 waves/SIMD possible); grid stays 683 x 3 tiles (all resident).

typedef __attribute__((ext_vector_type(8))) short short8v;
typedef __attribute__((ext_vector_type(4))) float float4v;

static __device__ __forceinline__ short f2bfs(float f) {
  __hip_bfloat16 h = __float2bfloat16(f);   // native cvt, RNE
  return *reinterpret_cast<short*>(&h);
}
static __device__ __forceinline__ float bfs2f(short s) {
  return __uint_as_float(((unsigned)(unsigned short)s) << 16);
}
static __device__ __forceinline__ unsigned short f2bf(float f) {
  unsigned int u = __float_as_uint(f);
  unsigned int r = (u + 0x7fffu + ((u >> 16) & 1u)) >> 16;
  return (unsigned short)r;
}

// ---------------- prepE: MLPs + all MLP-independent tables (flat) ---------
__global__ __launch_bounds__(128) void prepE(
    const float* __restrict__ color_embed, const float* __restrict__ row_embed,
    const float* __restrict__ col_embed,
    const float* __restrict__ ip_w1, const float* __restrict__ ip_b1,
    const float* __restrict__ ip_w2, const float* __restrict__ ip_b2,
    const float* __restrict__ op_w1, const float* __restrict__ op_b1,
    const float* __restrict__ op_w2, const float* __restrict__ op_b2,
    const float* __restrict__ q_w, const float* __restrict__ q_b,
    const float* __restrict__ o_w, const float* __restrict__ o_b,
    const float* __restrict__ cb_w1, const float* __restrict__ cb_b1,
    const float* __restrict__ cb_w2,
    float* __restrict__ inpval, float* __restrict__ outval,
    float* __restrict__ qtab, float* __restrict__ cpeproj,
    float* __restrict__ bias1,
    unsigned short* __restrict__ wovT, unsigned short* __restrict__ cbw2T) {
  const int bid = blockIdx.x, t = threadIdx.x;
  if (bid < 200) {                         // MLP for cij (input / output path)
    __shared__ float feat[128];
    __shared__ float h1[128];
    const int path = bid / 100;
    const int cij = bid % 100;
    const int c = cij / 25, ij = cij % 25, gi = ij / 5, gj = ij % 5;
    if (t < 64)      feat[t] = color_embed[c * 64 + t];
    else if (t < 96) feat[t] = row_embed[gi * 32 + (t - 64)];
    else             feat[t] = col_embed[gj * 32 + (t - 96)];
    __syncthreads();
    const float* w1 = path ? op_w1 : ip_w1;
    const float* b1 = path ? op_b1 : ip_b1;
    float acc = b1[t];
#pragma unroll 8
    for (int d = 0; d < 128; ++d) acc = fmaf(feat[d], w1[d * 128 + t], acc);
    h1[t] = fmaxf(acc, 0.f);
    __syncthreads();
    if (t < 64) {
      const float* w2 = path ? op_w2 : ip_w2;
      const float* b2 = path ? op_b2 : ip_b2;
      float v = b2[t];
#pragma unroll 8
      for (int d = 0; d < 128; ++d) v = fmaf(h1[d], w2[d * 64 + t], v);
      (path ? outval : inpval)[cij * 64 + t] = v;
    }
    return;
  }
  // flat one-output-per-thread sections
  const int fid = (bid - 200) * 128 + t;
  if (fid < 1664) {                        // qtab[26][64]
    const int p = fid >> 6, e2 = fid & 63;
    float a = q_b[e2];
    if (p < 25) {
      const int r = p / 5, cc = p % 5;
#pragma unroll 8
      for (int e = 0; e < 32; ++e) a = fmaf(row_embed[r * 32 + e], q_w[e * 64 + e2], a);
#pragma unroll 8
      for (int e = 0; e < 32; ++e) a = fmaf(col_embed[cc * 32 + e], q_w[(32 + e) * 64 + e2], a);
    }
    qtab[fid] = a;
  } else if (fid < 4992) {                 // cpeproj[26][128]
    const int l = fid - 1664;
    const int p = l >> 7, jj = l & 127;
    float a = 0.f;
    if (p < 25) {
      const int r = p / 5, cc = p % 5;
#pragma unroll 8
      for (int e = 0; e < 32; ++e) a = fmaf(row_embed[r * 32 + e], cb_w1[(128 + e) * 128 + jj], a);
#pragma unroll 8
      for (int e = 0; e < 32; ++e) a = fmaf(col_embed[cc * 32 + e], cb_w1[(160 + e) * 128 + jj], a);
    }
    cpeproj[l] = a;
  } else if (fid < 5120) {                 // bias1[128]
    const int jj = fid - 4992;
    float a = cb_b1[jj];
#pragma unroll 8
    for (int e = 0; e < 64; ++e) a = fmaf(o_b[e], cb_w1[e * 128 + jj], a);
    bias1[jj] = a;
  } else if (fid < 13312) {                // wovT[col 128][d 64] = bf16(o_w@cb_w1)
    const int i = fid - 5120;
    const int col = i >> 6, d = i & 63;
    float a = 0.f;
#pragma unroll 8
    for (int e = 0; e < 64; ++e) a = fmaf(o_w[d * 64 + e], cb_w1[e * 128 + col], a);
    wovT[i] = f2bf(a);
  } else if (fid < 29696) {                // cbw2T[col 128][k 128]
    const int i = fid - 13312;
    const int col = i >> 7, k = i & 127;
    cbw2T[i] = f2bf(cb_w2[k * 128 + col]);
  }
}

// ---------------- prepF: per-cij k/v/outproj + stab; aux rows --------------
__global__ __launch_bounds__(256) void prepF(
    const float* __restrict__ k_w, const float* __restrict__ k_b,
    const float* __restrict__ v_w, const float* __restrict__ v_b,
    const float* __restrict__ cb_w1,
    const float* __restrict__ qtab, const float* __restrict__ cpeproj,
    const float* __restrict__ bias1,
    const float* __restrict__ inpval, const float* __restrict__ outval,
    float* __restrict__ stab, unsigned short* __restrict__ vtabT,
    unsigned short* __restrict__ outprojBT) {
  const int bid = blockIdx.x, t = threadIdx.x;
  if (bid < 100) {
    __shared__ float kk[64];
    const int ig = bid / 25, ij = bid % 25;   // color, cell
    const float* x = inpval + bid * 64;
    if (t < 64) {                            // k column -> LDS
      float a = k_b[t];
#pragma unroll 8
      for (int e = 0; e < 64; ++e) a = fmaf(x[e], k_w[e * 64 + t], a);
      kk[t] = a;
    } else if (t < 128) {                    // v column -> vtabT direct (k'=4ij+ig)
      const int e2 = t - 64;
      float a = v_b[e2];
#pragma unroll 8
      for (int e = 0; e < 64; ++e) a = fmaf(x[e], v_w[e * 64 + e2], a);
      vtabT[(e2 >> 4) * 2048 + (e2 & 15) * 128 + 4 * ij + ig] = f2bf(a);
    } else {                                 // outproj column -> outprojBT direct
      const int col = t - 128;
      const float* y = outval + bid * 64;
      float a = 0.f;
#pragma unroll 8
      for (int e = 0; e < 64; ++e) a = fmaf(y[e], cb_w1[(64 + e) * 128 + col], a);
      outprojBT[col * 128 + 4 * ij + ig] = f2bf(a * (1.f / 25.f));
    }
    __syncthreads();
    if (t < 104) {                           // stab slice for this (ig, ij)
      const int cpe = t >> 2, h = t & 3;
      const float* qq = qtab + cpe * 64 + h * 16;
      float a = 0.f;
#pragma unroll
      for (int d = 0; d < 16; ++d) a = fmaf(qq[d], kk[h * 16 + d], a);
      stab[cpe * 400 + ig * 100 + ij * 4 + h] = a * 0.25f;
    }
  } else {                                   // aux block
    if (t < 128) {                           // outprojBT rows 100..127
      for (int p = 0; p < 26; ++p)
        outprojBT[t * 128 + 100 + p] = f2bf(cpeproj[p * 128 + t]);
      outprojBT[t * 128 + 126] = f2bf(bias1[t]);
      outprojBT[t * 128 + 127] = 0;
    } else {                                 // zero vtabT k' rows 100..127
      for (int i = t - 128; i < 1792; i += 128) {
        const int h = i / 448, r = i % 448;
        const int d = r / 28, kp = 100 + r % 28;
        vtabT[h * 2048 + d * 128 + kp] = 0;
      }
    }
  }
}

// ---------------- arc_fused: 683 blocks x 3 tiles, natural VGPR -----------
__global__ __launch_bounds__(256) void arc_fused(
    const int* __restrict__ obs,
    const float* __restrict__ stab,
    const unsigned short* __restrict__ vtabT,
    const unsigned short* __restrict__ outprojBT,
    const unsigned short* __restrict__ wovT,
    const unsigned short* __restrict__ cbw2T,
    const float* __restrict__ cb_b2,
    float* __restrict__ out) {
  __shared__ __align__(16) short lds_w[4 * 16 * 128];    // 16 KB, swz by batch row
  __shared__ __align__(16) short lds_og[16 * 128];       // 4 KB
  __shared__ __align__(16) short lds_raH[16 * 64];       // 2 KB
  __shared__ __align__(16) short lds_hidH[16 * 128];     // 4 KB
  __shared__ __align__(16) short lds_hidL[16 * 128];     // 4 KB

  const int tid = threadIdx.x;
  const int lane = tid & 63, wv = tid >> 6;
  const int row16 = lane & 15, g4 = lane >> 4;
  const int hh = row16 >> 2, jj = row16 & 3;
  const int b_loc = wv * 4 + g4;
  const int rsw = (row16 & 7) << 4;
  const int bswz = (b_loc & 7) << 4;
  const int tbase = blockIdx.x * 3;          // first tile (of 2048) for this block

  // ---- hoist all B-fragments into registers (constant across tiles) ----
  short8v Bv[4], Bo[2][4], Bw[2][2], Bc[2][4];
#pragma unroll
  for (int ks = 0; ks < 4; ++ks)
    Bv[ks] = *(const short8v*)(vtabT + wv * 2048 + row16 * 128 + ks * 32 + g4 * 8);
#pragma unroll
  for (int t = 0; t < 2; ++t) {
    const int col = wv * 32 + t * 16 + row16;
#pragma unroll
    for (int ks = 0; ks < 4; ++ks) {
      Bo[t][ks] = *(const short8v*)(outprojBT + col * 128 + ks * 32 + g4 * 8);
      Bc[t][ks] = *(const short8v*)(cbw2T + col * 128 + ks * 32 + g4 * 8);
    }
#pragma unroll
    for (int ks = 0; ks < 2; ++ks)
      Bw[t][ks] = *(const short8v*)(wovT + col * 64 + ks * 32 + g4 * 8);
  }
  const float bv0 = cb_b2[wv * 32 + row16];
  const float bv1 = cb_b2[wv * 32 + 16 + row16];

  // ---- one-time zero of W (covers the never-scattered pad bytes) ----
  {
    const int4 z = {0, 0, 0, 0};
    int4* pw = (int4*)lds_w;
#pragma unroll
    for (int i = 0; i < 4; ++i) pw[tid + 256 * i] = z;
  }

  // ---- prefetch obs for tile 0 ----
  int xs[4], ys[4];
#pragma unroll
  for (int e = 0; e < 4; ++e) {
    const int* ob = obs + (tbase * 16 + wv * 4 + e) * 75;
    xs[e] = ob[lane];
    ys[e] = (lane < 11) ? ob[64 + lane] : 0;
  }
  __syncthreads();   // W zero visible to all

  for (int it = 0; it < 3; ++it) {
    const int gt = tbase + it;
    if (gt >= 2048) break;
    const int b0 = gt * 16;

    // ---- decode from prefetched obs ----
    unsigned iglo = 0, ighi = 0, oglo = 0, oghi = 0;
    int cpe_sel = 0;
#pragma unroll
    for (int e = 0; e < 4; ++e) {
      const unsigned long long blo = __ballot(xs[e] & 1);
      const unsigned long long bhi = __ballot(xs[e] & 2);
      const unsigned long long bnzy = __ballot((lane < 11) && (ys[e] != 0));
      const unsigned e_iglo = (unsigned)(blo & 0x1FFFFFFull);
      const unsigned e_ighi = (unsigned)(bhi & 0x1FFFFFFull);
      const unsigned e_oglo = (unsigned)((blo >> 25) & 0x1FFFFFFull);
      const unsigned e_oghi = (unsigned)((bhi >> 25) & 0x1FFFFFFull);
      const unsigned e_mb = (unsigned)(((blo | bhi) >> 50) | (bnzy << 14));
      const int e_cpe = e_mb ? __builtin_ctz(e_mb) : 25;
      if (g4 == e) { iglo = e_iglo; ighi = e_ighi; oglo = e_oglo; oghi = e_oghi; cpe_sel = e_cpe; }
    }

    // ---- softmax: thread-per-(batch, head hh, slot jj) ----
    float ev[7];
    int ig7[7];
    {
      float sv[7];
      float mx = -1e30f;
      const float* sb = stab + cpe_sel * 400 + hh;
#pragma unroll
      for (int m = 0; m < 7; ++m) {
        const int ij = jj + 4 * m;
        if (ij < 25) {
          const int ig = ((iglo >> ij) & 1) | (((ighi >> ij) & 1) << 1);
          ig7[m] = ig;
          sv[m] = sb[ig * 100 + ij * 4];
          mx = fmaxf(mx, sv[m]);
        }
      }
      mx = fmaxf(mx, __shfl_xor(mx, 1));
      mx = fmaxf(mx, __shfl_xor(mx, 2));
      float sum = 0.f;
#pragma unroll
      for (int m = 0; m < 7; ++m) {
        const int ij = jj + 4 * m;
        if (ij < 25) { ev[m] = __expf(sv[m] - mx); sum += ev[m]; }
      }
      sum += __shfl_xor(sum, 1);
      sum += __shfl_xor(sum, 2);
      const float inv = __builtin_amdgcn_rcpf(sum);
#pragma unroll
      for (int m = 0; m < 7; ++m) ev[m] *= inv;
    }

    // ---- scatter W: thread owns k' = 4*(jj+4m)+0..3 (8B each), m=0..6 ----
#pragma unroll
    for (int m = 0; m < 7; ++m) {
      const int ij = jj + 4 * m;
      unsigned u0 = 0, u1 = 0;
      if (ij < 25) {
        const unsigned pbu = (unsigned)(unsigned short)f2bfs(ev[m]);
        const int ig = ig7[m];
        u0 = (ig == 0) ? pbu : ((ig == 1) ? (pbu << 16) : 0u);
        u1 = (ig == 2) ? pbu : ((ig == 3) ? (pbu << 16) : 0u);
      }
      const int off = (hh * 4096 + b_loc * 256 + 8 * ij) ^ bswz;
      *(int2*)((char*)lds_w + off) = make_int2((int)u0, (int)u1);
    }

    // ---- scatter OG row b_loc: thread row16 owns k' = 8*row16..+8 (16B) ----
    {
      unsigned sh[8];
#pragma unroll
      for (int u = 0; u < 8; ++u) {
        const int kp = row16 * 8 + u;
        unsigned v = 0;
        if (kp < 100) {
          const int ijq = kp >> 2;
          const int og = ((oglo >> ijq) & 1) | (((oghi >> ijq) & 1) << 1);
          v = (og == (kp & 3)) ? 0x3F80u : 0u;
        } else if (kp < 126) {
          v = (cpe_sel == kp - 100) ? 0x3F80u : 0u;
        } else if (kp == 126) {
          v = 0x3F80u;
        }
        sh[u] = v;
      }
      int4 pk;
      pk.x = (int)(sh[0] | (sh[1] << 16));
      pk.y = (int)(sh[2] | (sh[3] << 16));
      pk.z = (int)(sh[4] | (sh[5] << 16));
      pk.w = (int)(sh[6] | (sh[7] << 16));
      const int off = (b_loc * 256 + row16 * 16) ^ bswz;
      *(int4*)((char*)lds_og + off) = pk;
    }
    __syncthreads();   // B1: W/OG ready

    // ---- ra-GEMM (W rows = batches, head wv) + pre-GEMM (OG rows) ----
    float4v rc = {0.f, 0.f, 0.f, 0.f};
#pragma unroll
    for (int ks = 0; ks < 4; ++ks) {
      const short8v a = *(const short8v*)((char*)lds_w +
          ((wv * 4096 + row16 * 256 + ks * 64 + g4 * 16) ^ rsw));
      rc = __builtin_amdgcn_mfma_f32_16x16x32_bf16(a, Bv[ks], rc, 0, 0, 0);
    }
    float4v acc[2];
    acc[0] = (float4v){0.f, 0.f, 0.f, 0.f};
    acc[1] = (float4v){0.f, 0.f, 0.f, 0.f};
#pragma unroll
    for (int ks = 0; ks < 4; ++ks) {
      const short8v a = *(const short8v*)((char*)lds_og +
          ((row16 * 256 + ks * 64 + g4 * 16) ^ rsw));
      acc[0] = __builtin_amdgcn_mfma_f32_16x16x32_bf16(a, Bo[0][ks], acc[0], 0, 0, 0);
      acc[1] = __builtin_amdgcn_mfma_f32_16x16x32_bf16(a, Bo[1][ks], acc[1], 0, 0, 0);
    }

    // ---- prefetch next tile's obs (hides HBM latency under MFMA phase) ----
    if (it < 2 && gt + 1 < 2048) {
#pragma unroll
      for (int e = 0; e < 4; ++e) {
        const int* ob = obs + ((gt + 1) * 16 + wv * 4 + e) * 75;
        xs[e] = ob[lane];
        ys[e] = (lane < 11) ? ob[64 + lane] : 0;
      }
    }

    // ---- ra -> LDS (hi only) ----
#pragma unroll
    for (int r = 0; r < 4; ++r) {
      const int b = g4 * 4 + r;
      const int off = (b * 128 + (wv * 16 + row16) * 2) ^ ((b & 7) << 4);
      *(short*)((char*)lds_raH + off) = f2bfs(rc[r]);
    }
    __syncthreads();   // B2: ra ready; W/OG reads done

    // ---- wov-GEMM ----
    const short8v aH0 = *(const short8v*)((char*)lds_raH + ((row16 * 128 + g4 * 16) ^ rsw));
    const short8v aH1 = *(const short8v*)((char*)lds_raH + ((row16 * 128 + 64 + g4 * 16) ^ rsw));
#pragma unroll
    for (int t = 0; t < 2; ++t) {
      acc[t] = __builtin_amdgcn_mfma_f32_16x16x32_bf16(aH0, Bw[t][0], acc[t], 0, 0, 0);
      acc[t] = __builtin_amdgcn_mfma_f32_16x16x32_bf16(aH1, Bw[t][1], acc[t], 0, 0, 0);
    }

    // ---- relu -> hidden bf16 hi+lo ----
#pragma unroll
    for (int t = 0; t < 2; ++t) {
      const int col = wv * 32 + t * 16 + row16;
#pragma unroll
      for (int rr = 0; rr < 4; ++rr) {
        const int row = g4 * 4 + rr;
        const float hv = fmaxf(acc[t][rr], 0.f);
        const short hb = f2bfs(hv);
        const int off = (row * 256 + col * 2) ^ ((row & 7) << 4);
        *(short*)((char*)lds_hidH + off) = hb;
        *(short*)((char*)lds_hidL + off) = f2bfs(hv - bfs2f(hb));
      }
    }
    __syncthreads();   // B3: hidden ready

    // ---- out-GEMM ----
    short8v ahH[4], ahL[4];
#pragma unroll
    for (int ks = 0; ks < 4; ++ks) {
      const int off = (row16 * 256 + ks * 64 + g4 * 16) ^ rsw;
      ahH[ks] = *(const short8v*)((char*)lds_hidH + off);
      ahL[ks] = *(const short8v*)((char*)lds_hidL + off);
    }
#pragma unroll
    for (int t = 0; t < 2; ++t) {
      const int col = wv * 32 + t * 16 + row16;
      float4v c2 = {0.f, 0.f, 0.f, 0.f};
#pragma unroll
      for (int ks = 0; ks < 4; ++ks) {
        c2 = __builtin_amdgcn_mfma_f32_16x16x32_bf16(ahL[ks], Bc[t][ks], c2, 0, 0, 0);
        c2 = __builtin_amdgcn_mfma_f32_16x16x32_bf16(ahH[ks], Bc[t][ks], c2, 0, 0, 0);
      }
      const float bv = t ? bv1 : bv0;
#pragma unroll
      for (int rr = 0; rr < 4; ++rr)
        out[(b0 + g4 * 4 + rr) * 128 + col] = c2[rr] + bv;
    }
  }
}

extern "C" void kernel_launch(void* const* d_in, const int* in_sizes, int n_in,
                              void* d_out, int out_size, void* d_ws, size_t ws_size,
                              hipStream_t stream) {
  const int*   obs         = (const int*)d_in[0];
  const float* color_embed = (const float*)d_in[1];
  const float* row_embed   = (const float*)d_in[2];
  const float* col_embed   = (const float*)d_in[3];
  const float* ip_w1 = (const float*)d_in[4];
  const float* ip_b1 = (const float*)d_in[5];
  const float* ip_w2 = (const float*)d_in[6];
  const float* ip_b2 = (const float*)d_in[7];
  const float* q_w = (const float*)d_in[8];
  const float* q_b = (const float*)d_in[9];
  const float* k_w = (const float*)d_in[10];
  const float* k_b = (const float*)d_in[11];
  const float* v_w = (const float*)d_in[12];
  const float* v_b = (const float*)d_in[13];
  const float* o_w = (const float*)d_in[14];
  const float* o_b = (const float*)d_in[15];
  const float* op_w1 = (const float*)d_in[16];
  const float* op_b1 = (const float*)d_in[17];
  const float* op_w2 = (const float*)d_in[18];
  const float* op_b2 = (const float*)d_in[19];
  const float* cb_w1 = (const float*)d_in[20];
  const float* cb_b1 = (const float*)d_in[21];
  const float* cb_w2 = (const float*)d_in[22];
  const float* cb_b2 = (const float*)d_in[23];

  float* ws = (float*)d_ws;
  float* qtab    = ws;                 // 1664
  float* cpeproj = qtab + 1664;        // 3328
  float* bias1   = cpeproj + 3328;     // 128
  float* stab    = bias1 + 128;        // 10400  (ends at 15520)
  unsigned short* wovT      = (unsigned short*)(ws + 15520);  //  8192 us (4096 f)
  unsigned short* cbw2T     = (unsigned short*)(ws + 19616);  // 16384 us (8192 f)
  unsigned short* vtabT     = (unsigned short*)(ws + 27808);  //  8192 us (4096 f)
  unsigned short* outprojBT = (unsigned short*)(ws + 31904);  // 16384 us (8192 f)
  float* inpval  = ws + 40096;         // 6400
  float* outval  = inpval + 6400;      // 6400
  // total 52896 floats ~= 212 KB of d_ws

  prepE<<<432, 128, 0, stream>>>(color_embed, row_embed, col_embed,
                                 ip_w1, ip_b1, ip_w2, ip_b2,
                                 op_w1, op_b1, op_w2, op_b2,
                                 q_w, q_b, o_w, o_b, cb_w1, cb_b1, cb_w2,
                                 inpval, outval, qtab, cpeproj, bias1,
                                 wovT, cbw2T);
  prepF<<<101, 256, 0, stream>>>(k_w, k_b, v_w, v_b, cb_w1,
                                 qtab, cpeproj, bias1, inpval, outval,
                                 stab, vtabT, outprojBT);
  arc_fused<<<683, 256, 0, stream>>>(obs, stab, vtabT, outprojBT,
                                     wovT, cbw2T, cb_b2, (float*)d_out);
}

// Round 16
// 37.499 us; speedup vs baseline: 1.4976x; 1.1746x over previous
//
#include <hip/hip_runtime.h>
#include <hip/hip_bf16.h>

// PositionAwareARCEncoder fused kernels.
// B=32768, H=W=5, NC=4, E=64, HID=128, OUT=128, NH=4, HD=16.
//
// R15 = R12 verbatim (best measured config: 36.8 us).
//  - prepE (432x128): per-cij MLPs + flat qtab/cpeproj/bias1/wovT/cbw2T.
//  - prepF (101x256): per-cij k->stab / v->vtabT / outproj->outprojBT + aux.
//  - arc_fused (512x256, 4 tiles of 16 batches): B-frags hoisted once
//    (prologue amortized over 4 tiles -- grids >512 regressed: R9/R13/R14),
//    one-hot W/OG scatter (k'=4ij+sel, no zeroing), 3 barriers/tile,
//    MFMA chain: ra = W@vtabT, pre = OG@outprojBT, hidden = relu(pre+ra@wov),
//    out = hidden@cb_w2 + b2 (hidden bf16 hi+lo compensated).

typedef __attribute__((ext_vector_type(8))) short short8v;
typedef __attribute__((ext_vector_type(4))) float float4v;

static __device__ __forceinline__ short f2bfs(float f) {
  __hip_bfloat16 h = __float2bfloat16(f);   // native cvt, RNE
  return *reinterpret_cast<short*>(&h);
}
static __device__ __forceinline__ float bfs2f(short s) {
  return __uint_as_float(((unsigned)(unsigned short)s) << 16);
}
static __device__ __forceinline__ unsigned short f2bf(float f) {
  unsigned int u = __float_as_uint(f);
  unsigned int r = (u + 0x7fffu + ((u >> 16) & 1u)) >> 16;
  return (unsigned short)r;
}

// ---------------- prepE: MLPs + all MLP-independent tables (flat) ---------
__global__ __launch_bounds__(128) void prepE(
    const float* __restrict__ color_embed, const float* __restrict__ row_embed,
    const float* __restrict__ col_embed,
    const float* __restrict__ ip_w1, const float* __restrict__ ip_b1,
    const float* __restrict__ ip_w2, const float* __restrict__ ip_b2,
    const float* __restrict__ op_w1, const float* __restrict__ op_b1,
    const float* __restrict__ op_w2, const float* __restrict__ op_b2,
    const float* __restrict__ q_w, const float* __restrict__ q_b,
    const float* __restrict__ o_w, const float* __restrict__ o_b,
    const float* __restrict__ cb_w1, const float* __restrict__ cb_b1,
    const float* __restrict__ cb_w2,
    float* __restrict__ inpval, float* __restrict__ outval,
    float* __restrict__ qtab, float* __restrict__ cpeproj,
    float* __restrict__ bias1,
    unsigned short* __restrict__ wovT, unsigned short* __restrict__ cbw2T) {
  const int bid = blockIdx.x, t = threadIdx.x;
  if (bid < 200) {                         // MLP for cij (input / output path)
    __shared__ float feat[128];
    __shared__ float h1[128];
    const int path = bid / 100;
    const int cij = bid % 100;
    const int c = cij / 25, ij = cij % 25, gi = ij / 5, gj = ij % 5;
    if (t < 64)      feat[t] = color_embed[c * 64 + t];
    else if (t < 96) feat[t] = row_embed[gi * 32 + (t - 64)];
    else             feat[t] = col_embed[gj * 32 + (t - 96)];
    __syncthreads();
    const float* w1 = path ? op_w1 : ip_w1;
    const float* b1 = path ? op_b1 : ip_b1;
    float acc = b1[t];
#pragma unroll 8
    for (int d = 0; d < 128; ++d) acc = fmaf(feat[d], w1[d * 128 + t], acc);
    h1[t] = fmaxf(acc, 0.f);
    __syncthreads();
    if (t < 64) {
      const float* w2 = path ? op_w2 : ip_w2;
      const float* b2 = path ? op_b2 : ip_b2;
      float v = b2[t];
#pragma unroll 8
      for (int d = 0; d < 128; ++d) v = fmaf(h1[d], w2[d * 64 + t], v);
      (path ? outval : inpval)[cij * 64 + t] = v;
    }
    return;
  }
  // flat one-output-per-thread sections
  const int fid = (bid - 200) * 128 + t;
  if (fid < 1664) {                        // qtab[26][64]
    const int p = fid >> 6, e2 = fid & 63;
    float a = q_b[e2];
    if (p < 25) {
      const int r = p / 5, cc = p % 5;
#pragma unroll 8
      for (int e = 0; e < 32; ++e) a = fmaf(row_embed[r * 32 + e], q_w[e * 64 + e2], a);
#pragma unroll 8
      for (int e = 0; e < 32; ++e) a = fmaf(col_embed[cc * 32 + e], q_w[(32 + e) * 64 + e2], a);
    }
    qtab[fid] = a;
  } else if (fid < 4992) {                 // cpeproj[26][128]
    const int l = fid - 1664;
    const int p = l >> 7, jj = l & 127;
    float a = 0.f;
    if (p < 25) {
      const int r = p / 5, cc = p % 5;
#pragma unroll 8
      for (int e = 0; e < 32; ++e) a = fmaf(row_embed[r * 32 + e], cb_w1[(128 + e) * 128 + jj], a);
#pragma unroll 8
      for (int e = 0; e < 32; ++e) a = fmaf(col_embed[cc * 32 + e], cb_w1[(160 + e) * 128 + jj], a);
    }
    cpeproj[l] = a;
  } else if (fid < 5120) {                 // bias1[128]
    const int jj = fid - 4992;
    float a = cb_b1[jj];
#pragma unroll 8
    for (int e = 0; e < 64; ++e) a = fmaf(o_b[e], cb_w1[e * 128 + jj], a);
    bias1[jj] = a;
  } else if (fid < 13312) {                // wovT[col 128][d 64] = bf16(o_w@cb_w1)
    const int i = fid - 5120;
    const int col = i >> 6, d = i & 63;
    float a = 0.f;
#pragma unroll 8
    for (int e = 0; e < 64; ++e) a = fmaf(o_w[d * 64 + e], cb_w1[e * 128 + col], a);
    wovT[i] = f2bf(a);
  } else if (fid < 29696) {                // cbw2T[col 128][k 128]
    const int i = fid - 13312;
    const int col = i >> 7, k = i & 127;
    cbw2T[i] = f2bf(cb_w2[k * 128 + col]);
  }
}

// ---------------- prepF: per-cij k/v/outproj + stab; aux rows --------------
__global__ __launch_bounds__(256) void prepF(
    const float* __restrict__ k_w, const float* __restrict__ k_b,
    const float* __restrict__ v_w, const float* __restrict__ v_b,
    const float* __restrict__ cb_w1,
    const float* __restrict__ qtab, const float* __restrict__ cpeproj,
    const float* __restrict__ bias1,
    const float* __restrict__ inpval, const float* __restrict__ outval,
    float* __restrict__ stab, unsigned short* __restrict__ vtabT,
    unsigned short* __restrict__ outprojBT) {
  const int bid = blockIdx.x, t = threadIdx.x;
  if (bid < 100) {
    __shared__ float kk[64];
    const int ig = bid / 25, ij = bid % 25;   // color, cell
    const float* x = inpval + bid * 64;
    if (t < 64) {                            // k column -> LDS
      float a = k_b[t];
#pragma unroll 8
      for (int e = 0; e < 64; ++e) a = fmaf(x[e], k_w[e * 64 + t], a);
      kk[t] = a;
    } else if (t < 128) {                    // v column -> vtabT direct (k'=4ij+ig)
      const int e2 = t - 64;
      float a = v_b[e2];
#pragma unroll 8
      for (int e = 0; e < 64; ++e) a = fmaf(x[e], v_w[e * 64 + e2], a);
      vtabT[(e2 >> 4) * 2048 + (e2 & 15) * 128 + 4 * ij + ig] = f2bf(a);
    } else {                                 // outproj column -> outprojBT direct
      const int col = t - 128;
      const float* y = outval + bid * 64;
      float a = 0.f;
#pragma unroll 8
      for (int e = 0; e < 64; ++e) a = fmaf(y[e], cb_w1[(64 + e) * 128 + col], a);
      outprojBT[col * 128 + 4 * ij + ig] = f2bf(a * (1.f / 25.f));
    }
    __syncthreads();
    if (t < 104) {                           // stab slice for this (ig, ij)
      const int cpe = t >> 2, h = t & 3;
      const float* qq = qtab + cpe * 64 + h * 16;
      float a = 0.f;
#pragma unroll
      for (int d = 0; d < 16; ++d) a = fmaf(qq[d], kk[h * 16 + d], a);
      stab[cpe * 400 + ig * 100 + ij * 4 + h] = a * 0.25f;
    }
  } else {                                   // aux block
    if (t < 128) {                           // outprojBT rows 100..127
      for (int p = 0; p < 26; ++p)
        outprojBT[t * 128 + 100 + p] = f2bf(cpeproj[p * 128 + t]);
      outprojBT[t * 128 + 126] = f2bf(bias1[t]);
      outprojBT[t * 128 + 127] = 0;
    } else {                                 // zero vtabT k' rows 100..127
      for (int i = t - 128; i < 1792; i += 128) {
        const int h = i / 448, r = i % 448;
        const int d = r / 28, kp = 100 + r % 28;
        vtabT[h * 2048 + d * 128 + kp] = 0;
      }
    }
  }
}

// ---------------- arc_fused: R8/R12 proven kernel (512 blocks, 4 tiles) ---
__global__ __launch_bounds__(256) void arc_fused(
    const int* __restrict__ obs,
    const float* __restrict__ stab,
    const unsigned short* __restrict__ vtabT,
    const unsigned short* __restrict__ outprojBT,
    const unsigned short* __restrict__ wovT,
    const unsigned short* __restrict__ cbw2T,
    const float* __restrict__ cb_b2,
    float* __restrict__ out) {
  __shared__ __align__(16) short lds_w[4 * 16 * 128];    // 16 KB, swz by batch row
  __shared__ __align__(16) short lds_og[16 * 128];       // 4 KB
  __shared__ __align__(16) short lds_raH[16 * 64];       // 2 KB
  __shared__ __align__(16) short lds_hidH[16 * 128];     // 4 KB
  __shared__ __align__(16) short lds_hidL[16 * 128];     // 4 KB

  const int tid = threadIdx.x;
  const int lane = tid & 63, wv = tid >> 6;
  const int row16 = lane & 15, g4 = lane >> 4;
  const int hh = row16 >> 2, jj = row16 & 3;
  const int b_loc = wv * 4 + g4;
  const int rsw = (row16 & 7) << 4;
  const int bswz = (b_loc & 7) << 4;
  const int bbase = blockIdx.x * 64;

  // ---- hoist all B-fragments into registers (constant across tiles) ----
  short8v Bv[4], Bo[2][4], Bw[2][2], Bc[2][4];
#pragma unroll
  for (int ks = 0; ks < 4; ++ks)
    Bv[ks] = *(const short8v*)(vtabT + wv * 2048 + row16 * 128 + ks * 32 + g4 * 8);
#pragma unroll
  for (int t = 0; t < 2; ++t) {
    const int col = wv * 32 + t * 16 + row16;
#pragma unroll
    for (int ks = 0; ks < 4; ++ks) {
      Bo[t][ks] = *(const short8v*)(outprojBT + col * 128 + ks * 32 + g4 * 8);
      Bc[t][ks] = *(const short8v*)(cbw2T + col * 128 + ks * 32 + g4 * 8);
    }
#pragma unroll
    for (int ks = 0; ks < 2; ++ks)
      Bw[t][ks] = *(const short8v*)(wovT + col * 64 + ks * 32 + g4 * 8);
  }
  const float bv0 = cb_b2[wv * 32 + row16];
  const float bv1 = cb_b2[wv * 32 + 16 + row16];

  // ---- one-time zero of W (covers the never-scattered pad bytes) ----
  {
    const int4 z = {0, 0, 0, 0};
    int4* pw = (int4*)lds_w;
#pragma unroll
    for (int i = 0; i < 4; ++i) pw[tid + 256 * i] = z;
  }

  // ---- prefetch obs for tile 0 ----
  int xs[4], ys[4];
#pragma unroll
  for (int e = 0; e < 4; ++e) {
    const int* ob = obs + (bbase + wv * 4 + e) * 75;
    xs[e] = ob[lane];
    ys[e] = (lane < 11) ? ob[64 + lane] : 0;
  }
  __syncthreads();   // W zero visible to all

  for (int it = 0; it < 4; ++it) {
    const int b0 = bbase + it * 16;

    // ---- decode from prefetched obs ----
    unsigned iglo = 0, ighi = 0, oglo = 0, oghi = 0;
    int cpe_sel = 0;
#pragma unroll
    for (int e = 0; e < 4; ++e) {
      const unsigned long long blo = __ballot(xs[e] & 1);
      const unsigned long long bhi = __ballot(xs[e] & 2);
      const unsigned long long bnzy = __ballot((lane < 11) && (ys[e] != 0));
      const unsigned e_iglo = (unsigned)(blo & 0x1FFFFFFull);
      const unsigned e_ighi = (unsigned)(bhi & 0x1FFFFFFull);
      const unsigned e_oglo = (unsigned)((blo >> 25) & 0x1FFFFFFull);
      const unsigned e_oghi = (unsigned)((bhi >> 25) & 0x1FFFFFFull);
      const unsigned e_mb = (unsigned)(((blo | bhi) >> 50) | (bnzy << 14));
      const int e_cpe = e_mb ? __builtin_ctz(e_mb) : 25;
      if (g4 == e) { iglo = e_iglo; ighi = e_ighi; oglo = e_oglo; oghi = e_oghi; cpe_sel = e_cpe; }
    }

    // ---- softmax: thread-per-(batch, head hh, slot jj) ----
    float ev[7];
    int ig7[7];
    {
      float sv[7];
      float mx = -1e30f;
      const float* sb = stab + cpe_sel * 400 + hh;
#pragma unroll
      for (int m = 0; m < 7; ++m) {
        const int ij = jj + 4 * m;
        if (ij < 25) {
          const int ig = ((iglo >> ij) & 1) | (((ighi >> ij) & 1) << 1);
          ig7[m] = ig;
          sv[m] = sb[ig * 100 + ij * 4];
          mx = fmaxf(mx, sv[m]);
        }
      }
      mx = fmaxf(mx, __shfl_xor(mx, 1));
      mx = fmaxf(mx, __shfl_xor(mx, 2));
      float sum = 0.f;
#pragma unroll
      for (int m = 0; m < 7; ++m) {
        const int ij = jj + 4 * m;
        if (ij < 25) { ev[m] = __expf(sv[m] - mx); sum += ev[m]; }
      }
      sum += __shfl_xor(sum, 1);
      sum += __shfl_xor(sum, 2);
      const float inv = __builtin_amdgcn_rcpf(sum);
#pragma unroll
      for (int m = 0; m < 7; ++m) ev[m] *= inv;
    }

    // ---- scatter W: thread owns k' = 4*(jj+4m)+0..3 (8B each), m=0..6 ----
#pragma unroll
    for (int m = 0; m < 7; ++m) {
      const int ij = jj + 4 * m;
      unsigned u0 = 0, u1 = 0;
      if (ij < 25) {
        const unsigned pbu = (unsigned)(unsigned short)f2bfs(ev[m]);
        const int ig = ig7[m];
        u0 = (ig == 0) ? pbu : ((ig == 1) ? (pbu << 16) : 0u);
        u1 = (ig == 2) ? pbu : ((ig == 3) ? (pbu << 16) : 0u);
      }
      const int off = (hh * 4096 + b_loc * 256 + 8 * ij) ^ bswz;
      *(int2*)((char*)lds_w + off) = make_int2((int)u0, (int)u1);
    }

    // ---- scatter OG row b_loc: thread row16 owns k' = 8*row16..+8 (16B) ----
    {
      unsigned sh[8];
#pragma unroll
      for (int u = 0; u < 8; ++u) {
        const int kp = row16 * 8 + u;
        unsigned v = 0;
        if (kp < 100) {
          const int ijq = kp >> 2;
          const int og = ((oglo >> ijq) & 1) | (((oghi >> ijq) & 1) << 1);
          v = (og == (kp & 3)) ? 0x3F80u : 0u;
        } else if (kp < 126) {
          v = (cpe_sel == kp - 100) ? 0x3F80u : 0u;
        } else if (kp == 126) {
          v = 0x3F80u;
        }
        sh[u] = v;
      }
      int4 pk;
      pk.x = (int)(sh[0] | (sh[1] << 16));
      pk.y = (int)(sh[2] | (sh[3] << 16));
      pk.z = (int)(sh[4] | (sh[5] << 16));
      pk.w = (int)(sh[6] | (sh[7] << 16));
      const int off = (b_loc * 256 + row16 * 16) ^ bswz;
      *(int4*)((char*)lds_og + off) = pk;
    }
    __syncthreads();   // B1: W/OG ready

    // ---- ra-GEMM (W rows = batches, head wv) + pre-GEMM (OG rows) ----
    float4v rc = {0.f, 0.f, 0.f, 0.f};
#pragma unroll
    for (int ks = 0; ks < 4; ++ks) {
      const short8v a = *(const short8v*)((char*)lds_w +
          ((wv * 4096 + row16 * 256 + ks * 64 + g4 * 16) ^ rsw));
      rc = __builtin_amdgcn_mfma_f32_16x16x32_bf16(a, Bv[ks], rc, 0, 0, 0);
    }
    float4v acc[2];
    acc[0] = (float4v){0.f, 0.f, 0.f, 0.f};
    acc[1] = (float4v){0.f, 0.f, 0.f, 0.f};
#pragma unroll
    for (int ks = 0; ks < 4; ++ks) {
      const short8v a = *(const short8v*)((char*)lds_og +
          ((row16 * 256 + ks * 64 + g4 * 16) ^ rsw));
      acc[0] = __builtin_amdgcn_mfma_f32_16x16x32_bf16(a, Bo[0][ks], acc[0], 0, 0, 0);
      acc[1] = __builtin_amdgcn_mfma_f32_16x16x32_bf16(a, Bo[1][ks], acc[1], 0, 0, 0);
    }

    // ---- prefetch next tile's obs (hides HBM latency under MFMA phase) ----
    if (it < 3) {
#pragma unroll
      for (int e = 0; e < 4; ++e) {
        const int* ob = obs + (bbase + (it + 1) * 16 + wv * 4 + e) * 75;
        xs[e] = ob[lane];
        ys[e] = (lane < 11) ? ob[64 + lane] : 0;
      }
    }

    // ---- ra -> LDS (hi only) ----
#pragma unroll
    for (int r = 0; r < 4; ++r) {
      const int b = g4 * 4 + r;
      const int off = (b * 128 + (wv * 16 + row16) * 2) ^ ((b & 7) << 4);
      *(short*)((char*)lds_raH + off) = f2bfs(rc[r]);
    }
    __syncthreads();   // B2: ra ready; W/OG reads done

    // ---- wov-GEMM ----
    const short8v aH0 = *(const short8v*)((char*)lds_raH + ((row16 * 128 + g4 * 16) ^ rsw));
    const short8v aH1 = *(const short8v*)((char*)lds_raH + ((row16 * 128 + 64 + g4 * 16) ^ rsw));
#pragma unroll
    for (int t = 0; t < 2; ++t) {
      acc[t] = __builtin_amdgcn_mfma_f32_16x16x32_bf16(aH0, Bw[t][0], acc[t], 0, 0, 0);
      acc[t] = __builtin_amdgcn_mfma_f32_16x16x32_bf16(aH1, Bw[t][1], acc[t], 0, 0, 0);
    }

    // ---- relu -> hidden bf16 hi+lo ----
#pragma unroll
    for (int t = 0; t < 2; ++t) {
      const int col = wv * 32 + t * 16 + row16;
#pragma unroll
      for (int rr = 0; rr < 4; ++rr) {
        const int row = g4 * 4 + rr;
        const float hv = fmaxf(acc[t][rr], 0.f);
        const short hb = f2bfs(hv);
        const int off = (row * 256 + col * 2) ^ ((row & 7) << 4);
        *(short*)((char*)lds_hidH + off) = hb;
        *(short*)((char*)lds_hidL + off) = f2bfs(hv - bfs2f(hb));
      }
    }
    __syncthreads();   // B3: hidden ready

    // ---- out-GEMM ----
    short8v ahH[4], ahL[4];
#pragma unroll
    for (int ks = 0; ks < 4; ++ks) {
      const int off = (row16 * 256 + ks * 64 + g4 * 16) ^ rsw;
      ahH[ks] = *(const short8v*)((char*)lds_hidH + off);
      ahL[ks] = *(const short8v*)((char*)lds_hidL + off);
    }
#pragma unroll
    for (int t = 0; t < 2; ++t) {
      const int col = wv * 32 + t * 16 + row16;
      float4v c2 = {0.f, 0.f, 0.f, 0.f};
#pragma unroll
      for (int ks = 0; ks < 4; ++ks) {
        c2 = __builtin_amdgcn_mfma_f32_16x16x32_bf16(ahL[ks], Bc[t][ks], c2, 0, 0, 0);
        c2 = __builtin_amdgcn_mfma_f32_16x16x32_bf16(ahH[ks], Bc[t][ks], c2, 0, 0, 0);
      }
      const float bv = t ? bv1 : bv0;
#pragma unroll
      for (int rr = 0; rr < 4; ++rr)
        out[(b0 + g4 * 4 + rr) * 128 + col] = c2[rr] + bv;
    }
  }
}

extern "C" void kernel_launch(void* const* d_in, const int* in_sizes, int n_in,
                              void* d_out, int out_size, void* d_ws, size_t ws_size,
                              hipStream_t stream) {
  const int*   obs         = (const int*)d_in[0];
  const float* color_embed = (const float*)d_in[1];
  const float* row_embed   = (const float*)d_in[2];
  const float* col_embed   = (const float*)d_in[3];
  const float* ip_w1 = (const float*)d_in[4];
  const float* ip_b1 = (const float*)d_in[5];
  const float* ip_w2 = (const float*)d_in[6];
  const float* ip_b2 = (const float*)d_in[7];
  const float* q_w = (const float*)d_in[8];
  const float* q_b = (const float*)d_in[9];
  const float* k_w = (const float*)d_in[10];
  const float* k_b = (const float*)d_in[11];
  const float* v_w = (const float*)d_in[12];
  const float* v_b = (const float*)d_in[13];
  const float* o_w = (const float*)d_in[14];
  const float* o_b = (const float*)d_in[15];
  const float* op_w1 = (const float*)d_in[16];
  const float* op_b1 = (const float*)d_in[17];
  const float* op_w2 = (const float*)d_in[18];
  const float* op_b2 = (const float*)d_in[19];
  const float* cb_w1 = (const float*)d_in[20];
  const float* cb_b1 = (const float*)d_in[21];
  const float* cb_w2 = (const float*)d_in[22];
  const float* cb_b2 = (const float*)d_in[23];

  float* ws = (float*)d_ws;
  float* qtab    = ws;                 // 1664
  float* cpeproj = qtab + 1664;        // 3328
  float* bias1   = cpeproj + 3328;     // 128
  float* stab    = bias1 + 128;        // 10400  (ends at 15520)
  unsigned short* wovT      = (unsigned short*)(ws + 15520);  //  8192 us (4096 f)
  unsigned short* cbw2T     = (unsigned short*)(ws + 19616);  // 16384 us (8192 f)
  unsigned short* vtabT     = (unsigned short*)(ws + 27808);  //  8192 us (4096 f)
  unsigned short* outprojBT = (unsigned short*)(ws + 31904);  // 16384 us (8192 f)
  float* inpval  = ws + 40096;         // 6400
  float* outval  = inpval + 6400;      // 6400
  // total 52896 floats ~= 212 KB of d_ws

  prepE<<<432, 128, 0, stream>>>(color_embed, row_embed, col_embed,
                                 ip_w1, ip_b1, ip_w2, ip_b2,
                                 op_w1, op_b1, op_w2, op_b2,
                                 q_w, q_b, o_w, o_b, cb_w1, cb_b1, cb_w2,
                                 inpval, outval, qtab, cpeproj, bias1,
                                 wovT, cbw2T);
  prepF<<<101, 256, 0, stream>>>(k_w, k_b, v_w, v_b, cb_w1,
                                 qtab, cpeproj, bias1, inpval, outval,
                                 stab, vtabT, outprojBT);
  arc_fused<<<512, 256, 0, stream>>>(obs, stab, vtabT, outprojBT,
                                     wovT, cbw2T, cb_b2, (float*)d_out);
}